// Round 6
// baseline (5300.319 us; speedup 1.0000x reference)
//
#include <hip/hip_runtime.h>
#include <hip/hip_bf16.h>
#include <math.h>

#define E_DIM 1024
#define H_DIM 2048
#define H3 6144
#define VOCAB 256
#define NCOMP 256          // one WG per CU
#define TPW 512            // 8 waves; wave uu owns hidden unit base+uu
#define NXCD 8

typedef unsigned long long u64;
typedef unsigned int u32;
typedef u32 u32x4 __attribute__((ext_vector_type(4)));

// ---------------- Phase A: table[v][j] = b_ih[j] + sum_e emb[v,e]*w_ih[j,e]
__global__ __launch_bounds__(256) void ih_table_kernel(
    const float* __restrict__ emb, const float* __restrict__ w_ih,
    const float* __restrict__ b_ih, float* __restrict__ table)
{
    __shared__ float As[32][65];
    __shared__ float Bs[32][65];
    const int v0 = blockIdx.y * 64;
    const int j0 = blockIdx.x * 64;
    const int t  = threadIdx.x;
    const int tx = t % 16, ty = t / 16;
    const int lr0 = t / 8;
    const int lc  = (t % 8) * 4;
    float acc[4][4] = {};

    for (int k0 = 0; k0 < E_DIM; k0 += 32) {
        __syncthreads();
#pragma unroll
        for (int p = 0; p < 2; ++p) {
            int r = lr0 + p * 32;
            float4 a = *(const float4*)(emb  + (size_t)(v0 + r) * E_DIM + k0 + lc);
            As[lc+0][r] = a.x; As[lc+1][r] = a.y; As[lc+2][r] = a.z; As[lc+3][r] = a.w;
            float4 b = *(const float4*)(w_ih + (size_t)(j0 + r) * E_DIM + k0 + lc);
            Bs[lc+0][r] = b.x; Bs[lc+1][r] = b.y; Bs[lc+2][r] = b.z; Bs[lc+3][r] = b.w;
        }
        __syncthreads();
#pragma unroll 8
        for (int kk = 0; kk < 32; ++kk) {
            float a4[4], b4[4];
#pragma unroll
            for (int i = 0; i < 4; ++i) a4[i] = As[kk][ty * 4 + i];
#pragma unroll
            for (int i = 0; i < 4; ++i) b4[i] = Bs[kk][tx * 4 + i];
#pragma unroll
            for (int i = 0; i < 4; ++i)
#pragma unroll
                for (int j = 0; j < 4; ++j) acc[i][j] += a4[i] * b4[j];
        }
    }
    const int j = j0 + tx * 4;
    float4 bias = *(const float4*)(b_ih + j);
#pragma unroll
    for (int i = 0; i < 4; ++i) {
        int v = v0 + ty * 4 + i;
        float4 o;
        o.x = acc[i][0] + bias.x; o.y = acc[i][1] + bias.y;
        o.z = acc[i][2] + bias.z; o.w = acc[i][3] + bias.w;
        *(float4*)(table + (size_t)v * H3 + j) = o;
    }
}

// ---------------- Phase B: persistent GRU, W_hh register-resident.
// R17: XCD-LOCAL L2 RELAY (R16 resubmit, hardened — R16 returned a bare
// harness exception, no kernel data). Structure: every level SINGLE-PHASE
// (discovery=data, tag travels with data in one 16B txn; R15 proved
// two-phase gating pays wave-slip twice).
//   * hub election: thread 0 reads HW_REG_XCC_ID and atomicAdd's
//     hubcnt[xcd]; first arriver is hub. Election is SELF-CONSISTENT
//     even if the ID is garbage (each masked group elects one hub from
//     its own members) — correctness never depends on the ID, only perf.
//   * hub (1/XCD): R14-style tagged poll of the global hbuf (sc0 sc1,
//     compression, sleep(1)); only ~8K txns/sweep chip-wide -> LLC
//     decongested -> ~700cy clean latency. Forwards its regs via plain
//     16B stores into the per-XCD double-buffered mirror (write-through
//     L1 -> local L2).
//   * consumers: same tagged poll on the mirror, sc0-only (L2-served,
//     ~360cy period). HARDENING vs R16: after 16 failed local sweeps a
//     thread falls back to the ground-truth GLOBAL poll — any locality
//     failure degrades to R14 speed instead of deadlocking.
//   * mirror parity reuse safe: hub reaches step s+2 only after every WG
//     published s+2's input, i.e. finished consuming step s.
__global__ __launch_bounds__(TPW, 2) void gru_persistent(
    const int* __restrict__ x, const int* __restrict__ lenp,
    const float* __restrict__ w_hh, const float* __restrict__ b_hh,
    const float* __restrict__ table,
    u64* hbuf0, u64* hbuf1, u64* mirrors, u32* hubcnt)
{
    __shared__ float hsh[2][H_DIM];   // double-buffered staged h
    __shared__ int   hubSh;
    __shared__ u64*  mirSh;
    const int cw   = blockIdx.x;
    const int tid  = threadIdx.x;
    const int base = cw * 8;
    const int uu   = tid >> 6;     // wave id = owned unit
    const int l    = tid & 63;     // lane
    const int S    = lenp[0] + 1;  // 1025

    // hub election on the (real) XCD id
    if (tid == 0) {
        u32 xcc;
        asm volatile("s_getreg_b32 %0, hwreg(HW_REG_XCC_ID)" : "=s"(xcc));
        xcc &= (NXCD - 1);
        u32 prev = atomicAdd(&hubcnt[xcc], 1u);
        hubSh = (prev == 0);
        mirSh = mirrors + (size_t)xcc * 2 * H_DIM;
    }
    __syncthreads();
    const bool isHub = (hubSh != 0);
    u64* const mir   = mirSh;

    // one-time weight preload: 3 gates x 8 float4 = 96 regs, pinned
    float4 wv[3][8];
#pragma unroll
    for (int g = 0; g < 3; ++g) {
        const float4* wr =
            (const float4*)(w_hh + (size_t)(g * H_DIM + base + uu) * H_DIM);
#pragma unroll
        for (int i = 0; i < 8; ++i) wv[g][i] = wr[i * 64 + l];
    }
#pragma unroll
    for (int g = 0; g < 3; ++g)
#pragma unroll
        for (int i = 0; i < 8; ++i)
            asm volatile("" : "+v"(wv[g][i].x), "+v"(wv[g][i].y),
                              "+v"(wv[g][i].z), "+v"(wv[g][i].w));

    float bhr = 0.f, bhz = 0.f, bhn = 0.f;
    if (l == 0) {
        bhr = b_hh[base + uu];
        bhz = b_hh[H_DIM + base + uu];
        bhn = b_hh[2 * H_DIM + base + uu];
    }

    u64* bufs[2] = {hbuf0, hbuf1};

    for (int s = 0; s < S; ++s) {
        const u64* src  = bufs[s & 1];
        u64*       dst  = bufs[(s + 1) & 1];
        u64*       msrc = mir + (size_t)(s & 1) * H_DIM;
        float*     hs   = hsh[s & 1];

        // input-side gate values: issue before the spin (latency overlaps)
        float ihr = 0.f, ihz = 0.f, ihn = 0.f;
        if (l == 0) {
            const float* trow = table + (size_t)x[s] * H3;
            ihr = trow[base + uu];
            ihz = trow[H_DIM + base + uu];
            ihn = trow[2 * H_DIM + base + uu];
        }

        const unsigned want = (unsigned)s;
        u32x4 a, b;

        if (isHub) {
            // hub: tagged poll of the GLOBAL buffer (LLC), then forward
            const u64* ps = src + 4 * tid;
            for (;;) {
                asm volatile(
                    "global_load_dwordx4 %0, %2, off sc0 sc1\n\t"
                    "global_load_dwordx4 %1, %2, off offset:16 sc0 sc1\n\t"
                    "s_waitcnt vmcnt(0)"
                    : "=&v"(a), "=&v"(b)
                    : "v"(ps)
                    : "memory");
                if ((a.y == want) & (a.w == want) &
                    (b.y == want) & (b.w == want)) break;
                __builtin_amdgcn_s_sleep(1);
            }
            // forward tagged data into the XCD-local mirror (plain stores
            // -> write-through L1 -> resident in this XCD's L2)
            u32x4* mp = (u32x4*)(msrc + 4 * tid);
            mp[0] = a;
            mp[1] = b;
        } else {
            // consumer: tagged poll of the LOCAL mirror (sc0 = L2-served).
            // Fallback to the global ground truth after 16 local misses so
            // a locality failure can never deadlock.
            const u64* ps = msrc + 4 * tid;
            const u64* gp = src + 4 * tid;
            int misses = 0;
            bool done = false;
            while (!done && misses < 16) {
                asm volatile(
                    "global_load_dwordx4 %0, %2, off sc0\n\t"
                    "global_load_dwordx4 %1, %2, off offset:16 sc0\n\t"
                    "s_waitcnt vmcnt(0)"
                    : "=&v"(a), "=&v"(b)
                    : "v"(ps)
                    : "memory");
                done = (a.y == want) & (a.w == want) &
                       (b.y == want) & (b.w == want);
                if (!done) { ++misses; __builtin_amdgcn_s_sleep(1); }
            }
            while (!done) {   // fallback: R14 global tagged poll
                asm volatile(
                    "global_load_dwordx4 %0, %2, off sc0 sc1\n\t"
                    "global_load_dwordx4 %1, %2, off offset:16 sc0 sc1\n\t"
                    "s_waitcnt vmcnt(0)"
                    : "=&v"(a), "=&v"(b)
                    : "v"(gp)
                    : "memory");
                done = (a.y == want) & (a.w == want) &
                       (b.y == want) & (b.w == want);
                if (!done) __builtin_amdgcn_s_sleep(2);
            }
        }

        float4 st;
        st.x = __uint_as_float(a.x);
        st.y = __uint_as_float(a.z);
        st.z = __uint_as_float(b.x);
        st.w = __uint_as_float(b.z);
        *(float4*)(hs + 4 * tid) = st;   // one ds_write_b128
        __syncthreads();   // the ONLY barrier per step

        // fused-gate dot for unit base+uu: each h chunk read once, 3 FMAs
        const float4* h4 = (const float4*)hs;
        float4 ar = make_float4(0.f, 0.f, 0.f, 0.f);
        float4 az = make_float4(0.f, 0.f, 0.f, 0.f);
        float4 an = make_float4(0.f, 0.f, 0.f, 0.f);
#pragma unroll
        for (int i = 0; i < 8; ++i) {
            float4 hv = h4[i * 64 + l];
            ar.x += wv[0][i].x * hv.x; ar.y += wv[0][i].y * hv.y;
            ar.z += wv[0][i].z * hv.z; ar.w += wv[0][i].w * hv.w;
            az.x += wv[1][i].x * hv.x; az.y += wv[1][i].y * hv.y;
            az.z += wv[1][i].z * hv.z; az.w += wv[1][i].w * hv.w;
            an.x += wv[2][i].x * hv.x; an.y += wv[2][i].y * hv.y;
            an.z += wv[2][i].z * hv.z; an.w += wv[2][i].w * hv.w;
        }
        float pr = (ar.x + ar.y) + (ar.z + ar.w);
        float pz = (az.x + az.y) + (az.z + az.w);
        float pn = (an.x + an.y) + (an.z + an.w);
#pragma unroll
        for (int d = 1; d < 64; d <<= 1) {
            pr += __shfl_xor(pr, d);
            pz += __shfl_xor(pz, d);
            pn += __shfl_xor(pn, d);
        }

        // lane 0: gates + immediate publish (device-visible store)
        if (l == 0) {
            float hprev = hs[base + uu];
            float hr = pr + bhr;
            float hz = pz + bhz;
            float hn = pn + bhn;
            float r_ = 1.f / (1.f + __expf(-(ihr + hr)));
            float z_ = 1.f / (1.f + __expf(-(ihz + hz)));
            float xn = ihn + r_ * hn;
            float axn = fabsf(xn), te = __expf(2.f * axn);
            float n_ = copysignf(1.f - 2.f / (te + 1.f), xn);
            float hnew = (1.f - z_) * n_ + z_ * hprev;
            u64 pack = ((u64)(unsigned)(s + 1) << 32) |
                       (u64)__float_as_uint(hnew);
            __hip_atomic_store(dst + base + uu, pack, __ATOMIC_RELAXED,
                               __HIP_MEMORY_SCOPE_AGENT);
        }
        // no trailing barrier: next step stages into the other hsh buffer
    }
}

// ---------------- Epilogue: out = [dec_emb[2] (1024) | h_final (2048)]
__global__ void epilogue_kernel(const int* __restrict__ lenp,
                                const float* __restrict__ dec_emb,
                                const u64* __restrict__ hbuf0,
                                const u64* __restrict__ hbuf1,
                                float* __restrict__ out)
{
    int i = blockIdx.x * blockDim.x + threadIdx.x;
    int S = lenp[0] + 1;
    const u64* hb = (S & 1) ? hbuf1 : hbuf0;
    if (i < E_DIM) out[i] = dec_emb[2 * E_DIM + i];
    else if (i < E_DIM + H_DIM)
        out[i] = __uint_as_float((unsigned)hb[i - E_DIM]);
}

extern "C" void kernel_launch(void* const* d_in, const int* in_sizes, int n_in,
                              void* d_out, int out_size, void* d_ws, size_t ws_size,
                              hipStream_t stream) {
    const int*   x       = (const int*)d_in[0];
    const int*   lenp    = (const int*)d_in[1];
    const float* emb     = (const float*)d_in[2];
    const float* w_ih    = (const float*)d_in[3];
    const float* w_hh    = (const float*)d_in[4];
    const float* b_ih    = (const float*)d_in[5];
    const float* b_hh    = (const float*)d_in[6];
    const float* dec_emb = (const float*)d_in[7];
    float* out = (float*)d_out;

    char* ws = (char*)d_ws;
    float* table  = (float*)ws;                              // 6,291,456 B
    u64*   hbuf0  = (u64*)(ws + (size_t)VOCAB * H3 * 4);     // 2048 u64
    u64*   hbuf1  = hbuf0 + H_DIM;                           // 2048 u64
    u32*   hubcnt = (u32*)(hbuf1 + H_DIM);                   // 8 u32
    // mirrors: 256-aligned, 8 XCDs x 2 parity x 2048 u64 = 256 KiB
    u64*   mirrors = (u64*)(ws + (size_t)VOCAB * H3 * 4 + 33024);

    // zero tagged h buffers (h_0 = {tag 0, 0.0f}) + hub counters.
    // mirrors need no init: poisoned tags never equal a valid step.
    hipMemsetAsync(hbuf0, 0,
                   (size_t)2 * H_DIM * sizeof(u64) + NXCD * sizeof(u32),
                   stream);

    dim3 gA(H3 / 64, VOCAB / 64);  // (96, 4)
    ih_table_kernel<<<gA, 256, 0, stream>>>(emb, w_ih, b_ih, table);

    gru_persistent<<<dim3(NCOMP), dim3(TPW), 0, stream>>>(
        x, lenp, w_hh, b_hh, table, hbuf0, hbuf1, mirrors, hubcnt);

    epilogue_kernel<<<12, 256, 0, stream>>>(lenp, dec_emb, hbuf0, hbuf1, out);
}

// Round 7
// 4617.629 us; speedup vs baseline: 1.1478x; 1.1478x over previous
//
#include <hip/hip_runtime.h>
#include <hip/hip_bf16.h>
#include <math.h>

#define E_DIM 1024
#define H_DIM 2048
#define H3 6144
#define VOCAB 256
#define NCOMP 128          // one WG per CU (128 of 256 CUs)
#define TPW 512            // 8 waves; wave uu owns units base+2uu, base+2uu+1
#define UPW 16             // units per WG

typedef unsigned long long u64;
typedef unsigned int u32;
typedef u32 u32x4 __attribute__((ext_vector_type(4)));

// ---------------- Phase A: table[v][j] = b_ih[j] + sum_e emb[v,e]*w_ih[j,e]
__global__ __launch_bounds__(256) void ih_table_kernel(
    const float* __restrict__ emb, const float* __restrict__ w_ih,
    const float* __restrict__ b_ih, float* __restrict__ table)
{
    __shared__ float As[32][65];
    __shared__ float Bs[32][65];
    const int v0 = blockIdx.y * 64;
    const int j0 = blockIdx.x * 64;
    const int t  = threadIdx.x;
    const int tx = t % 16, ty = t / 16;
    const int lr0 = t / 8;
    const int lc  = (t % 8) * 4;
    float acc[4][4] = {};

    for (int k0 = 0; k0 < E_DIM; k0 += 32) {
        __syncthreads();
#pragma unroll
        for (int p = 0; p < 2; ++p) {
            int r = lr0 + p * 32;
            float4 a = *(const float4*)(emb  + (size_t)(v0 + r) * E_DIM + k0 + lc);
            As[lc+0][r] = a.x; As[lc+1][r] = a.y; As[lc+2][r] = a.z; As[lc+3][r] = a.w;
            float4 b = *(const float4*)(w_ih + (size_t)(j0 + r) * E_DIM + k0 + lc);
            Bs[lc+0][r] = b.x; Bs[lc+1][r] = b.y; Bs[lc+2][r] = b.z; Bs[lc+3][r] = b.w;
        }
        __syncthreads();
#pragma unroll 8
        for (int kk = 0; kk < 32; ++kk) {
            float a4[4], b4[4];
#pragma unroll
            for (int i = 0; i < 4; ++i) a4[i] = As[kk][ty * 4 + i];
#pragma unroll
            for (int i = 0; i < 4; ++i) b4[i] = Bs[kk][tx * 4 + i];
#pragma unroll
            for (int i = 0; i < 4; ++i)
#pragma unroll
                for (int j = 0; j < 4; ++j) acc[i][j] += a4[i] * b4[j];
        }
    }
    const int j = j0 + tx * 4;
    float4 bias = *(const float4*)(b_ih + j);
#pragma unroll
    for (int i = 0; i < 4; ++i) {
        int v = v0 + ty * 4 + i;
        float4 o;
        o.x = acc[i][0] + bias.x; o.y = acc[i][1] + bias.y;
        o.z = acc[i][2] + bias.z; o.w = acc[i][3] + bias.w;
        *(float4*)(table + (size_t)v * H3 + j) = o;
    }
}

// ---------------- Phase B: persistent GRU, W_hh register-resident.
// R18: HALVED FAN-IN. R17 proved relays are serial-additive (hub pays
// R14's global-max detect, then ADDS forward+local-detect; 5200us). R14's
// floor is the all-to-all txn count: every WG reads the full tagged h
// (16KB = 1024 x 16B non-coalescing LLC txns) per step; 256 WGs -> 262K
// txns/step ~= 2-4Kcy of LLC service, the dominant term. R18 keeps R14's
// protocol BYTE-FOR-BYTE (single-phase, discovery=data, tagged u64,
// batched 2x dwordx4 poll, compression, sleep(4), double-buffered LDS,
// one barrier) and halves WG count: 128 WGs, each WAVE owns TWO units:
//   * weights 2x96=192 pinned regs + ~50 working <= 256/wave budget
//     (launch_bounds(512,2)); 1024-thread WGs would need <=128 -> infeasible
//   * dot-A then dot-B reusing accumulators (+8 ds_read_b128 ~ +100cy)
//   * gates computed ONCE in all lanes on cndmask-selected (lane&1? B:A)
//     operands — zero divergence, same gate cost as R14
//   * lane0 packs {hA,tag,hB,tag} -> ONE global_store_dwordx4 sc0 sc1
//     (each u64 {data,tag} intact -> tag atomicity preserved; publish
//     txns halve too)
// Chip-wide poll txns: 262K -> 131K/step. Predict ~4200-4500 cy/step.
__global__ __launch_bounds__(TPW, 2) void gru_persistent(
    const int* __restrict__ x, const int* __restrict__ lenp,
    const float* __restrict__ w_hh, const float* __restrict__ b_hh,
    const float* __restrict__ table,
    u64* hbuf0, u64* hbuf1)
{
    __shared__ float hsh[2][H_DIM];   // double-buffered staged h
    const int cw   = blockIdx.x;
    const int tid  = threadIdx.x;
    const int base = cw * UPW;
    const int uu   = tid >> 6;     // wave id; owns units base+2uu, base+2uu+1
    const int l    = tid & 63;     // lane
    const int S    = lenp[0] + 1;  // 1025
    const int myu  = base + 2 * uu + (l & 1);  // this lane's gate-path unit

    // one-time weight preload: 2 units x 3 gates x 8 float4 = 192 regs
    float4 wva[3][8], wvb[3][8];
#pragma unroll
    for (int g = 0; g < 3; ++g) {
        const float4* ra =
            (const float4*)(w_hh + (size_t)(g * H_DIM + base + 2 * uu) * H_DIM);
        const float4* rb = ra + (H_DIM / 4);
#pragma unroll
        for (int i = 0; i < 8; ++i) { wva[g][i] = ra[i * 64 + l]; wvb[g][i] = rb[i * 64 + l]; }
    }
#pragma unroll
    for (int g = 0; g < 3; ++g)
#pragma unroll
        for (int i = 0; i < 8; ++i) {
            asm volatile("" : "+v"(wva[g][i].x), "+v"(wva[g][i].y),
                              "+v"(wva[g][i].z), "+v"(wva[g][i].w));
            asm volatile("" : "+v"(wvb[g][i].x), "+v"(wvb[g][i].y),
                              "+v"(wvb[g][i].z), "+v"(wvb[g][i].w));
        }

    float bhr = 0.f, bhz = 0.f, bhn = 0.f;
    if (l < 2) {
        bhr = b_hh[myu];
        bhz = b_hh[H_DIM + myu];
        bhn = b_hh[2 * H_DIM + myu];
    }

    u64* bufs[2] = {hbuf0, hbuf1};

    for (int s = 0; s < S; ++s) {
        const u64* src = bufs[s & 1];
        u64*       dst = bufs[(s + 1) & 1];
        float*     hs  = hsh[s & 1];

        // input-side gate values: issue before the spin (latency overlaps)
        float ihr = 0.f, ihz = 0.f, ihn = 0.f;
        if (l < 2) {
            const float* trow = table + (size_t)x[s] * H3;
            ihr = trow[myu];
            ihz = trow[H_DIM + myu];
            ihn = trow[2 * H_DIM + myu];
        }

        const unsigned want = (unsigned)s;

        // batched tagged sweep (R14): thread owns u64 slots 4*tid..4*tid+3
        {
            const u64* ps = src + 4 * tid;
            u32x4 a, b;
            asm volatile("global_load_dwordx4 %0, %2, off sc0 sc1\n\t"
                         "global_load_dwordx4 %1, %2, off offset:16 sc0 sc1\n\t"
                         "s_waitcnt vmcnt(0)"
                         : "=&v"(a), "=&v"(b)
                         : "v"(ps)
                         : "memory");
            for (;;) {
                bool ok = (a.y == want) & (a.w == want) &
                          (b.y == want) & (b.w == want);
                if (ok) break;
                __builtin_amdgcn_s_sleep(4);
                asm volatile("global_load_dwordx4 %0, %2, off sc0 sc1\n\t"
                             "global_load_dwordx4 %1, %2, off offset:16 sc0 sc1\n\t"
                             "s_waitcnt vmcnt(0)"
                             : "=&v"(a), "=&v"(b)
                             : "v"(ps)
                             : "memory");
            }
            float4 st;
            st.x = __uint_as_float(a.x);
            st.y = __uint_as_float(a.z);
            st.z = __uint_as_float(b.x);
            st.w = __uint_as_float(b.z);
            *(float4*)(hs + 4 * tid) = st;   // one ds_write_b128
        }
        __syncthreads();   // the ONLY barrier per step

        const float4* h4 = (const float4*)hs;

        // ---- unit A dot (3 fused gates) ----
        float4 ar = make_float4(0.f, 0.f, 0.f, 0.f);
        float4 az = make_float4(0.f, 0.f, 0.f, 0.f);
        float4 an = make_float4(0.f, 0.f, 0.f, 0.f);
#pragma unroll
        for (int i = 0; i < 8; ++i) {
            float4 hv = h4[i * 64 + l];
            ar.x += wva[0][i].x * hv.x; ar.y += wva[0][i].y * hv.y;
            ar.z += wva[0][i].z * hv.z; ar.w += wva[0][i].w * hv.w;
            az.x += wva[1][i].x * hv.x; az.y += wva[1][i].y * hv.y;
            az.z += wva[1][i].z * hv.z; az.w += wva[1][i].w * hv.w;
            an.x += wva[2][i].x * hv.x; an.y += wva[2][i].y * hv.y;
            an.z += wva[2][i].z * hv.z; an.w += wva[2][i].w * hv.w;
        }
        float prA = (ar.x + ar.y) + (ar.z + ar.w);
        float pzA = (az.x + az.y) + (az.z + az.w);
        float pnA = (an.x + an.y) + (an.z + an.w);
#pragma unroll
        for (int d = 1; d < 64; d <<= 1) {
            prA += __shfl_xor(prA, d);
            pzA += __shfl_xor(pzA, d);
            pnA += __shfl_xor(pnA, d);
        }

        // ---- unit B dot (reuse accumulators) ----
        ar = make_float4(0.f, 0.f, 0.f, 0.f);
        az = make_float4(0.f, 0.f, 0.f, 0.f);
        an = make_float4(0.f, 0.f, 0.f, 0.f);
#pragma unroll
        for (int i = 0; i < 8; ++i) {
            float4 hv = h4[i * 64 + l];
            ar.x += wvb[0][i].x * hv.x; ar.y += wvb[0][i].y * hv.y;
            ar.z += wvb[0][i].z * hv.z; ar.w += wvb[0][i].w * hv.w;
            az.x += wvb[1][i].x * hv.x; az.y += wvb[1][i].y * hv.y;
            az.z += wvb[1][i].z * hv.z; az.w += wvb[1][i].w * hv.w;
            an.x += wvb[2][i].x * hv.x; an.y += wvb[2][i].y * hv.y;
            an.z += wvb[2][i].z * hv.z; an.w += wvb[2][i].w * hv.w;
        }
        float prB = (ar.x + ar.y) + (ar.z + ar.w);
        float pzB = (az.x + az.y) + (az.z + az.w);
        float pnB = (an.x + an.y) + (an.z + an.w);
#pragma unroll
        for (int d = 1; d < 64; d <<= 1) {
            prB += __shfl_xor(prB, d);
            pzB += __shfl_xor(pzB, d);
            pnB += __shfl_xor(pnB, d);
        }

        // gates once, in ALL lanes, on lane-parity-selected operands
        // (uniform code, different data -> zero divergence)
        const bool isB = (l & 1);
        float pr = isB ? prB : prA;
        float pz = isB ? pzB : pzA;
        float pn = isB ? pnB : pnA;
        float hprev = hs[base + 2 * uu + (l & 1)];
        float hr = pr + bhr;
        float hz = pz + bhz;
        float hn = pn + bhn;
        float r_ = 1.f / (1.f + __expf(-(ihr + hr)));
        float z_ = 1.f / (1.f + __expf(-(ihz + hz)));
        float xn = ihn + r_ * hn;
        float axn = fabsf(xn), te = __expf(2.f * axn);
        float n_ = copysignf(1.f - 2.f / (te + 1.f), xn);
        float hnew = (1.f - z_) * n_ + z_ * hprev;

        // lane0 packs both units + tags into ONE 16B device-coherent store
        float hB = __shfl(hnew, 1);
        if (l == 0) {
            u32x4 pk;
            pk.x = __float_as_uint(hnew); pk.y = (u32)(s + 1);
            pk.z = __float_as_uint(hB);   pk.w = (u32)(s + 1);
            u64* dp = dst + base + 2 * uu;   // 16B-aligned (even u64 index)
            asm volatile("global_store_dwordx4 %0, %1, off sc0 sc1"
                         :: "v"(dp), "v"(pk) : "memory");
        }
        // no trailing barrier: next step stages into the other hsh buffer
    }
}

// ---------------- Epilogue: out = [dec_emb[2] (1024) | h_final (2048)]
__global__ void epilogue_kernel(const int* __restrict__ lenp,
                                const float* __restrict__ dec_emb,
                                const u64* __restrict__ hbuf0,
                                const u64* __restrict__ hbuf1,
                                float* __restrict__ out)
{
    int i = blockIdx.x * blockDim.x + threadIdx.x;
    int S = lenp[0] + 1;
    const u64* hb = (S & 1) ? hbuf1 : hbuf0;
    if (i < E_DIM) out[i] = dec_emb[2 * E_DIM + i];
    else if (i < E_DIM + H_DIM)
        out[i] = __uint_as_float((unsigned)hb[i - E_DIM]);
}

extern "C" void kernel_launch(void* const* d_in, const int* in_sizes, int n_in,
                              void* d_out, int out_size, void* d_ws, size_t ws_size,
                              hipStream_t stream) {
    const int*   x       = (const int*)d_in[0];
    const int*   lenp    = (const int*)d_in[1];
    const float* emb     = (const float*)d_in[2];
    const float* w_ih    = (const float*)d_in[3];
    const float* w_hh    = (const float*)d_in[4];
    const float* b_ih    = (const float*)d_in[5];
    const float* b_hh    = (const float*)d_in[6];
    const float* dec_emb = (const float*)d_in[7];
    float* out = (float*)d_out;

    char* ws = (char*)d_ws;
    float* table = (float*)ws;                              // 6,291,456 B
    u64*   hbuf0 = (u64*)(ws + (size_t)VOCAB * H3 * 4);     // 2048 u64
    u64*   hbuf1 = hbuf0 + H_DIM;                           // 2048 u64

    // zero both tagged h buffers: h_0 = {tag 0, 0.0f} (ws poisoned 0xAA)
    hipMemsetAsync(hbuf0, 0, (size_t)2 * H_DIM * sizeof(u64), stream);

    dim3 gA(H3 / 64, VOCAB / 64);  // (96, 4)
    ih_table_kernel<<<gA, 256, 0, stream>>>(emb, w_ih, b_ih, table);

    gru_persistent<<<dim3(NCOMP), dim3(TPW), 0, stream>>>(
        x, lenp, w_hh, b_hh, table, hbuf0, hbuf1);

    epilogue_kernel<<<12, 256, 0, stream>>>(lenp, dec_emb, hbuf0, hbuf1, out);
}

// Round 8
// 2979.465 us; speedup vs baseline: 1.7790x; 1.5498x over previous
//
#include <hip/hip_runtime.h>
#include <hip/hip_bf16.h>
#include <math.h>

#define E_DIM 1024
#define H_DIM 2048
#define H3 6144
#define VOCAB 256
#define NCOMP 256          // one WG per CU
#define TPW 512            // 8 waves; wave uu owns hidden unit base+uu

typedef unsigned long long u64;
typedef unsigned int u32;
typedef u32 u32x4 __attribute__((ext_vector_type(4)));

// ---------------- Phase A: table[v][j] = b_ih[j] + sum_e emb[v,e]*w_ih[j,e]
__global__ __launch_bounds__(256) void ih_table_kernel(
    const float* __restrict__ emb, const float* __restrict__ w_ih,
    const float* __restrict__ b_ih, float* __restrict__ table)
{
    __shared__ float As[32][65];
    __shared__ float Bs[32][65];
    const int v0 = blockIdx.y * 64;
    const int j0 = blockIdx.x * 64;
    const int t  = threadIdx.x;
    const int tx = t % 16, ty = t / 16;
    const int lr0 = t / 8;
    const int lc  = (t % 8) * 4;
    float acc[4][4] = {};

    for (int k0 = 0; k0 < E_DIM; k0 += 32) {
        __syncthreads();
#pragma unroll
        for (int p = 0; p < 2; ++p) {
            int r = lr0 + p * 32;
            float4 a = *(const float4*)(emb  + (size_t)(v0 + r) * E_DIM + k0 + lc);
            As[lc+0][r] = a.x; As[lc+1][r] = a.y; As[lc+2][r] = a.z; As[lc+3][r] = a.w;
            float4 b = *(const float4*)(w_ih + (size_t)(j0 + r) * E_DIM + k0 + lc);
            Bs[lc+0][r] = b.x; Bs[lc+1][r] = b.y; Bs[lc+2][r] = b.z; Bs[lc+3][r] = b.w;
        }
        __syncthreads();
#pragma unroll 8
        for (int kk = 0; kk < 32; ++kk) {
            float a4[4], b4[4];
#pragma unroll
            for (int i = 0; i < 4; ++i) a4[i] = As[kk][ty * 4 + i];
#pragma unroll
            for (int i = 0; i < 4; ++i) b4[i] = Bs[kk][tx * 4 + i];
#pragma unroll
            for (int i = 0; i < 4; ++i)
#pragma unroll
                for (int j = 0; j < 4; ++j) acc[i][j] += a4[i] * b4[j];
        }
    }
    const int j = j0 + tx * 4;
    float4 bias = *(const float4*)(b_ih + j);
#pragma unroll
    for (int i = 0; i < 4; ++i) {
        int v = v0 + ty * 4 + i;
        float4 o;
        o.x = acc[i][0] + bias.x; o.y = acc[i][1] + bias.y;
        o.z = acc[i][2] + bias.z; o.w = acc[i][3] + bias.w;
        *(float4*)(table + (size_t)v * H3 + j) = o;
    }
}

// ---------------- Phase B: persistent GRU, W_hh register-resident.
// R19: R14 (best, 2360us) with the per-step __syncthreads replaced by
// SPLIT-HALF LDS FLAGS. R18 showed fan-in reduction is register-infeasible
// (192 pinned regs spill, VGPR_Count=128). R14's leading barrier makes
// every wave wait on the WG-wide max of slot arrivals before ANY compute.
// But the dot consumes h in two independent halves: hs[0..1024) is staged
// by waves 0-3, hs[1024..2048) by waves 4-7. So:
//   * each wave, after its ds_write_b128 (+lgkmcnt(0) drain), RELEASE-
//     stores wflags[uu] = s (monotonic, workgroup scope)
//   * consumers ACQUIRE-spin flags{0..3} -> dot half1 -> spin flags{4..7}
//     -> dot half2: half2's straggler wait overlaps half1's compute
// Safety (no barrier needed at all): flags>=s for all 8 waves => every
// thread staged s => finished s-1 compute => LDS parity reuse safe; and
// the global tag protocol is unchanged — any WG publishing s+2 into a
// parity buffer transitively requires every WG to have fully staged s.
// Poll / backoff / publish byte-identical to R14.
__global__ __launch_bounds__(TPW, 2) void gru_persistent(
    const int* __restrict__ x, const int* __restrict__ lenp,
    const float* __restrict__ w_hh, const float* __restrict__ b_hh,
    const float* __restrict__ table,
    u64* hbuf0, u64* hbuf1)
{
    __shared__ float hsh[2][H_DIM];   // double-buffered staged h
    __shared__ int   wflags[8];       // last step staged, per wave
    const int cw   = blockIdx.x;
    const int tid  = threadIdx.x;
    const int base = cw * 8;
    const int uu   = tid >> 6;     // wave id = owned unit
    const int l    = tid & 63;     // lane
    const int S    = lenp[0] + 1;  // 1025

    // one-time weight preload: 3 gates x 8 float4 = 96 regs, pinned
    float4 wv[3][8];
#pragma unroll
    for (int g = 0; g < 3; ++g) {
        const float4* wr =
            (const float4*)(w_hh + (size_t)(g * H_DIM + base + uu) * H_DIM);
#pragma unroll
        for (int i = 0; i < 8; ++i) wv[g][i] = wr[i * 64 + l];
    }
#pragma unroll
    for (int g = 0; g < 3; ++g)
#pragma unroll
        for (int i = 0; i < 8; ++i)
            asm volatile("" : "+v"(wv[g][i].x), "+v"(wv[g][i].y),
                              "+v"(wv[g][i].z), "+v"(wv[g][i].w));

    float bhr = 0.f, bhz = 0.f, bhn = 0.f;
    if (l == 0) {
        bhr = b_hh[base + uu];
        bhz = b_hh[H_DIM + base + uu];
        bhn = b_hh[2 * H_DIM + base + uu];
    }

    if (tid < 8) wflags[tid] = -1;
    __syncthreads();   // one-time init barrier only

    u64* bufs[2] = {hbuf0, hbuf1};

    for (int s = 0; s < S; ++s) {
        const u64* src = bufs[s & 1];
        u64*       dst = bufs[(s + 1) & 1];
        float*     hs  = hsh[s & 1];

        // input-side gate values: issue before the spin (latency overlaps)
        float ihr = 0.f, ihz = 0.f, ihn = 0.f;
        if (l == 0) {
            const float* trow = table + (size_t)x[s] * H3;
            ihr = trow[base + uu];
            ihz = trow[H_DIM + base + uu];
            ihn = trow[2 * H_DIM + base + uu];
        }

        const unsigned want = (unsigned)s;

        // batched tagged sweep (R14): thread owns u64 slots 4*tid..4*tid+3
        {
            const u64* ps = src + 4 * tid;
            u32x4 a, b;
            asm volatile("global_load_dwordx4 %0, %2, off sc0 sc1\n\t"
                         "global_load_dwordx4 %1, %2, off offset:16 sc0 sc1\n\t"
                         "s_waitcnt vmcnt(0)"
                         : "=&v"(a), "=&v"(b)
                         : "v"(ps)
                         : "memory");
            for (;;) {
                bool ok = (a.y == want) & (a.w == want) &
                          (b.y == want) & (b.w == want);
                if (ok) break;
                __builtin_amdgcn_s_sleep(4);
                asm volatile("global_load_dwordx4 %0, %2, off sc0 sc1\n\t"
                             "global_load_dwordx4 %1, %2, off offset:16 sc0 sc1\n\t"
                             "s_waitcnt vmcnt(0)"
                             : "=&v"(a), "=&v"(b)
                             : "v"(ps)
                             : "memory");
            }
            float4 st;
            st.x = __uint_as_float(a.x);
            st.y = __uint_as_float(a.z);
            st.z = __uint_as_float(b.x);
            st.w = __uint_as_float(b.z);
            *(float4*)(hs + 4 * tid) = st;   // one ds_write_b128
        }
        // my wave's slots staged: drain ds, raise my flag (release)
        asm volatile("s_waitcnt lgkmcnt(0)" ::: "memory");
        if (l == 0)
            __hip_atomic_store(&wflags[uu], s, __ATOMIC_RELEASE,
                               __HIP_MEMORY_SCOPE_WORKGROUP);

        const float4* h4 = (const float4*)hs;
        float4 ar = make_float4(0.f, 0.f, 0.f, 0.f);
        float4 az = make_float4(0.f, 0.f, 0.f, 0.f);
        float4 an = make_float4(0.f, 0.f, 0.f, 0.f);

        // ---- wait half1 (waves 0-3 staged hs[0..1024)) then dot it ----
        for (;;) {
            int f0 = __hip_atomic_load(&wflags[0], __ATOMIC_ACQUIRE,
                                       __HIP_MEMORY_SCOPE_WORKGROUP);
            int f1 = __hip_atomic_load(&wflags[1], __ATOMIC_ACQUIRE,
                                       __HIP_MEMORY_SCOPE_WORKGROUP);
            int f2 = __hip_atomic_load(&wflags[2], __ATOMIC_ACQUIRE,
                                       __HIP_MEMORY_SCOPE_WORKGROUP);
            int f3 = __hip_atomic_load(&wflags[3], __ATOMIC_ACQUIRE,
                                       __HIP_MEMORY_SCOPE_WORKGROUP);
            if ((f0 >= s) & (f1 >= s) & (f2 >= s) & (f3 >= s)) break;
            __builtin_amdgcn_s_sleep(1);
        }
#pragma unroll
        for (int i = 0; i < 4; ++i) {
            float4 hv = h4[i * 64 + l];
            ar.x += wv[0][i].x * hv.x; ar.y += wv[0][i].y * hv.y;
            ar.z += wv[0][i].z * hv.z; ar.w += wv[0][i].w * hv.w;
            az.x += wv[1][i].x * hv.x; az.y += wv[1][i].y * hv.y;
            az.z += wv[1][i].z * hv.z; az.w += wv[1][i].w * hv.w;
            an.x += wv[2][i].x * hv.x; an.y += wv[2][i].y * hv.y;
            an.z += wv[2][i].z * hv.z; an.w += wv[2][i].w * hv.w;
        }

        // ---- wait half2 (waves 4-7 staged hs[1024..2048)) then dot it ----
        for (;;) {
            int f4 = __hip_atomic_load(&wflags[4], __ATOMIC_ACQUIRE,
                                       __HIP_MEMORY_SCOPE_WORKGROUP);
            int f5 = __hip_atomic_load(&wflags[5], __ATOMIC_ACQUIRE,
                                       __HIP_MEMORY_SCOPE_WORKGROUP);
            int f6 = __hip_atomic_load(&wflags[6], __ATOMIC_ACQUIRE,
                                       __HIP_MEMORY_SCOPE_WORKGROUP);
            int f7 = __hip_atomic_load(&wflags[7], __ATOMIC_ACQUIRE,
                                       __HIP_MEMORY_SCOPE_WORKGROUP);
            if ((f4 >= s) & (f5 >= s) & (f6 >= s) & (f7 >= s)) break;
            __builtin_amdgcn_s_sleep(1);
        }
#pragma unroll
        for (int i = 4; i < 8; ++i) {
            float4 hv = h4[i * 64 + l];
            ar.x += wv[0][i].x * hv.x; ar.y += wv[0][i].y * hv.y;
            ar.z += wv[0][i].z * hv.z; ar.w += wv[0][i].w * hv.w;
            az.x += wv[1][i].x * hv.x; az.y += wv[1][i].y * hv.y;
            az.z += wv[1][i].z * hv.z; az.w += wv[1][i].w * hv.w;
            an.x += wv[2][i].x * hv.x; an.y += wv[2][i].y * hv.y;
            an.z += wv[2][i].z * hv.z; an.w += wv[2][i].w * hv.w;
        }

        float pr = (ar.x + ar.y) + (ar.z + ar.w);
        float pz = (az.x + az.y) + (az.z + az.w);
        float pn = (an.x + an.y) + (an.z + an.w);
#pragma unroll
        for (int d = 1; d < 64; d <<= 1) {
            pr += __shfl_xor(pr, d);
            pz += __shfl_xor(pz, d);
            pn += __shfl_xor(pn, d);
        }

        // lane 0: gates + immediate publish
        if (l == 0) {
            float hprev = hs[base + uu];
            float hr = pr + bhr;
            float hz = pz + bhz;
            float hn = pn + bhn;
            float r_ = 1.f / (1.f + __expf(-(ihr + hr)));
            float z_ = 1.f / (1.f + __expf(-(ihz + hz)));
            float xn = ihn + r_ * hn;
            float axn = fabsf(xn), te = __expf(2.f * axn);
            float n_ = copysignf(1.f - 2.f / (te + 1.f), xn);
            float hnew = (1.f - z_) * n_ + z_ * hprev;
            u64 pack = ((u64)(unsigned)(s + 1) << 32) |
                       (u64)__float_as_uint(hnew);
            __hip_atomic_store(dst + base + uu, pack, __ATOMIC_RELAXED,
                               __HIP_MEMORY_SCOPE_AGENT);
        }
        // no barrier: parity + flag monotonicity keep LDS/global reuse safe
    }
}

// ---------------- Epilogue: out = [dec_emb[2] (1024) | h_final (2048)]
__global__ void epilogue_kernel(const int* __restrict__ lenp,
                                const float* __restrict__ dec_emb,
                                const u64* __restrict__ hbuf0,
                                const u64* __restrict__ hbuf1,
                                float* __restrict__ out)
{
    int i = blockIdx.x * blockDim.x + threadIdx.x;
    int S = lenp[0] + 1;
    const u64* hb = (S & 1) ? hbuf1 : hbuf0;
    if (i < E_DIM) out[i] = dec_emb[2 * E_DIM + i];
    else if (i < E_DIM + H_DIM)
        out[i] = __uint_as_float((unsigned)hb[i - E_DIM]);
}

extern "C" void kernel_launch(void* const* d_in, const int* in_sizes, int n_in,
                              void* d_out, int out_size, void* d_ws, size_t ws_size,
                              hipStream_t stream) {
    const int*   x       = (const int*)d_in[0];
    const int*   lenp    = (const int*)d_in[1];
    const float* emb     = (const float*)d_in[2];
    const float* w_ih    = (const float*)d_in[3];
    const float* w_hh    = (const float*)d_in[4];
    const float* b_ih    = (const float*)d_in[5];
    const float* b_hh    = (const float*)d_in[6];
    const float* dec_emb = (const float*)d_in[7];
    float* out = (float*)d_out;

    char* ws = (char*)d_ws;
    float* table = (float*)ws;                              // 6,291,456 B
    u64*   hbuf0 = (u64*)(ws + (size_t)VOCAB * H3 * 4);     // 2048 u64
    u64*   hbuf1 = hbuf0 + H_DIM;                           // 2048 u64

    // zero both tagged h buffers: h_0 = {tag 0, 0.0f} (ws poisoned 0xAA)
    hipMemsetAsync(hbuf0, 0, (size_t)2 * H_DIM * sizeof(u64), stream);

    dim3 gA(H3 / 64, VOCAB / 64);  // (96, 4)
    ih_table_kernel<<<gA, 256, 0, stream>>>(emb, w_ih, b_ih, table);

    gru_persistent<<<dim3(NCOMP), dim3(TPW), 0, stream>>>(
        x, lenp, w_hh, b_hh, table, hbuf0, hbuf1);

    epilogue_kernel<<<12, 256, 0, stream>>>(lenp, dec_emb, hbuf0, hbuf1, out);
}

// Round 9
// 2464.070 us; speedup vs baseline: 2.1510x; 1.2092x over previous
//
#include <hip/hip_runtime.h>
#include <hip/hip_bf16.h>
#include <math.h>

#define E_DIM 1024
#define H_DIM 2048
#define H3 6144
#define VOCAB 256
#define NCOMP 256          // one WG per CU
#define TPW 512            // 8 waves; wave uu owns hidden unit base+uu

typedef unsigned long long u64;
typedef unsigned int u32;
typedef u32 u32x4 __attribute__((ext_vector_type(4)));

// ---------------- Phase A: table[v][j] = b_ih[j] + sum_e emb[v,e]*w_ih[j,e]
__global__ __launch_bounds__(256) void ih_table_kernel(
    const float* __restrict__ emb, const float* __restrict__ w_ih,
    const float* __restrict__ b_ih, float* __restrict__ table)
{
    __shared__ float As[32][65];
    __shared__ float Bs[32][65];
    const int v0 = blockIdx.y * 64;
    const int j0 = blockIdx.x * 64;
    const int t  = threadIdx.x;
    const int tx = t % 16, ty = t / 16;
    const int lr0 = t / 8;
    const int lc  = (t % 8) * 4;
    float acc[4][4] = {};

    for (int k0 = 0; k0 < E_DIM; k0 += 32) {
        __syncthreads();
#pragma unroll
        for (int p = 0; p < 2; ++p) {
            int r = lr0 + p * 32;
            float4 a = *(const float4*)(emb  + (size_t)(v0 + r) * E_DIM + k0 + lc);
            As[lc+0][r] = a.x; As[lc+1][r] = a.y; As[lc+2][r] = a.z; As[lc+3][r] = a.w;
            float4 b = *(const float4*)(w_ih + (size_t)(j0 + r) * E_DIM + k0 + lc);
            Bs[lc+0][r] = b.x; Bs[lc+1][r] = b.y; Bs[lc+2][r] = b.z; Bs[lc+3][r] = b.w;
        }
        __syncthreads();
#pragma unroll 8
        for (int kk = 0; kk < 32; ++kk) {
            float a4[4], b4[4];
#pragma unroll
            for (int i = 0; i < 4; ++i) a4[i] = As[kk][ty * 4 + i];
#pragma unroll
            for (int i = 0; i < 4; ++i) b4[i] = Bs[kk][tx * 4 + i];
#pragma unroll
            for (int i = 0; i < 4; ++i)
#pragma unroll
                for (int j = 0; j < 4; ++j) acc[i][j] += a4[i] * b4[j];
        }
    }
    const int j = j0 + tx * 4;
    float4 bias = *(const float4*)(b_ih + j);
#pragma unroll
    for (int i = 0; i < 4; ++i) {
        int v = v0 + ty * 4 + i;
        float4 o;
        o.x = acc[i][0] + bias.x; o.y = acc[i][1] + bias.y;
        o.z = acc[i][2] + bias.z; o.w = acc[i][3] + bias.w;
        *(float4*)(table + (size_t)v * H3 + j) = o;
    }
}

// ---------------- Phase B: persistent GRU, W_hh register-resident.
// R20: R14 (best, 2360us/dispatch) with ONE change — the retry backoff.
// R19 post-mortem: replacing s_barrier with LDS flag-spins LOST 520us
// (s_barrier sleeps waves for free; software spin costs issue slots and
// breaks ds_read pipelining) -> intra-WG wait is NOT the bottleneck.
// Remaining R14 budget (~5530cy/step): compute ~800 + visibility ~400 +
// detect RT ~800 leaves ~2500-3500cy = 2-3 retry PERIODS (sleep(4)=256 +
// ~800cy congested load RT ~= 1050cy each): consumers enter the poll
// before data exists (first sweep always stale) and both mean detection
// and the barrier's 512-thread max quantize in period units.
// R20 backoff schedule: first gap keeps sleep(4) (skips the certainly-
// stale window cheaply), all later gaps sleep(1) -> period ~870cy and the
// detection tail tracks arrival within ~1 RT. Traffic +30-50% (compression
// still active; far from R12's 4x no-compression knee).
__global__ __launch_bounds__(TPW, 2) void gru_persistent(
    const int* __restrict__ x, const int* __restrict__ lenp,
    const float* __restrict__ w_hh, const float* __restrict__ b_hh,
    const float* __restrict__ table,
    u64* hbuf0, u64* hbuf1)
{
    __shared__ float hsh[2][H_DIM];   // double-buffered staged h
    const int cw   = blockIdx.x;
    const int tid  = threadIdx.x;
    const int base = cw * 8;
    const int uu   = tid >> 6;     // wave id = owned unit
    const int l    = tid & 63;     // lane
    const int S    = lenp[0] + 1;  // 1025

    // one-time weight preload: 3 gates x 8 float4 = 96 regs, pinned
    float4 wv[3][8];
#pragma unroll
    for (int g = 0; g < 3; ++g) {
        const float4* wr =
            (const float4*)(w_hh + (size_t)(g * H_DIM + base + uu) * H_DIM);
#pragma unroll
        for (int i = 0; i < 8; ++i) wv[g][i] = wr[i * 64 + l];
    }
#pragma unroll
    for (int g = 0; g < 3; ++g)
#pragma unroll
        for (int i = 0; i < 8; ++i)
            asm volatile("" : "+v"(wv[g][i].x), "+v"(wv[g][i].y),
                              "+v"(wv[g][i].z), "+v"(wv[g][i].w));

    float bhr = 0.f, bhz = 0.f, bhn = 0.f;
    if (l == 0) {
        bhr = b_hh[base + uu];
        bhz = b_hh[H_DIM + base + uu];
        bhn = b_hh[2 * H_DIM + base + uu];
    }

    u64* bufs[2] = {hbuf0, hbuf1};

    for (int s = 0; s < S; ++s) {
        const u64* src = bufs[s & 1];
        u64*       dst = bufs[(s + 1) & 1];
        float*     hs  = hsh[s & 1];

        // input-side gate values: issue before the spin (latency overlaps)
        float ihr = 0.f, ihz = 0.f, ihn = 0.f;
        if (l == 0) {
            const float* trow = table + (size_t)x[s] * H3;
            ihr = trow[base + uu];
            ihz = trow[H_DIM + base + uu];
            ihn = trow[2 * H_DIM + base + uu];
        }

        // batched tagged sweep: thread owns u64 slots 4*tid..4*tid+3.
        // Two 16B loads issued back-to-back, ONE vmcnt drain; each 16B =
        // {data0,tag0,data1,tag1}. Backoff: 4 then 1,1,1,...
        {
            const unsigned want = (unsigned)s;
            const u64* ps = src + 4 * tid;
            u32x4 a, b;
            asm volatile("global_load_dwordx4 %0, %2, off sc0 sc1\n\t"
                         "global_load_dwordx4 %1, %2, off offset:16 sc0 sc1\n\t"
                         "s_waitcnt vmcnt(0)"
                         : "=&v"(a), "=&v"(b)
                         : "v"(ps)
                         : "memory");
            bool ok = (a.y == want) & (a.w == want) &
                      (b.y == want) & (b.w == want);
            if (!ok) {
                __builtin_amdgcn_s_sleep(4);
                for (;;) {
                    asm volatile("global_load_dwordx4 %0, %2, off sc0 sc1\n\t"
                                 "global_load_dwordx4 %1, %2, off offset:16 sc0 sc1\n\t"
                                 "s_waitcnt vmcnt(0)"
                                 : "=&v"(a), "=&v"(b)
                                 : "v"(ps)
                                 : "memory");
                    ok = (a.y == want) & (a.w == want) &
                         (b.y == want) & (b.w == want);
                    if (ok) break;
                    __builtin_amdgcn_s_sleep(1);
                }
            }
            float4 st;
            st.x = __uint_as_float(a.x);
            st.y = __uint_as_float(a.z);
            st.z = __uint_as_float(b.x);
            st.w = __uint_as_float(b.z);
            *(float4*)(hs + 4 * tid) = st;   // one ds_write_b128
        }
        __syncthreads();   // the ONLY barrier per step

        // fused-gate dot for unit base+uu: each h chunk read once, 3 FMAs
        const float4* h4 = (const float4*)hs;
        float4 ar = make_float4(0.f, 0.f, 0.f, 0.f);
        float4 az = make_float4(0.f, 0.f, 0.f, 0.f);
        float4 an = make_float4(0.f, 0.f, 0.f, 0.f);
#pragma unroll
        for (int i = 0; i < 8; ++i) {
            float4 hv = h4[i * 64 + l];
            ar.x += wv[0][i].x * hv.x; ar.y += wv[0][i].y * hv.y;
            ar.z += wv[0][i].z * hv.z; ar.w += wv[0][i].w * hv.w;
            az.x += wv[1][i].x * hv.x; az.y += wv[1][i].y * hv.y;
            az.z += wv[1][i].z * hv.z; az.w += wv[1][i].w * hv.w;
            an.x += wv[2][i].x * hv.x; an.y += wv[2][i].y * hv.y;
            an.z += wv[2][i].z * hv.z; an.w += wv[2][i].w * hv.w;
        }
        float pr = (ar.x + ar.y) + (ar.z + ar.w);
        float pz = (az.x + az.y) + (az.z + az.w);
        float pn = (an.x + an.y) + (an.z + an.w);
#pragma unroll
        for (int d = 1; d < 64; d <<= 1) {
            pr += __shfl_xor(pr, d);
            pz += __shfl_xor(pz, d);
            pn += __shfl_xor(pn, d);
        }

        // lane 0: gates + immediate publish
        if (l == 0) {
            float hprev = hs[base + uu];
            float hr = pr + bhr;
            float hz = pz + bhz;
            float hn = pn + bhn;
            float r_ = 1.f / (1.f + __expf(-(ihr + hr)));
            float z_ = 1.f / (1.f + __expf(-(ihz + hz)));
            float xn = ihn + r_ * hn;
            float axn = fabsf(xn), te = __expf(2.f * axn);
            float n_ = copysignf(1.f - 2.f / (te + 1.f), xn);
            float hnew = (1.f - z_) * n_ + z_ * hprev;
            u64 pack = ((u64)(unsigned)(s + 1) << 32) |
                       (u64)__float_as_uint(hnew);
            __hip_atomic_store(dst + base + uu, pack, __ATOMIC_RELAXED,
                               __HIP_MEMORY_SCOPE_AGENT);
        }
        // no trailing barrier: next step stages into the other hsh buffer
    }
}

// ---------------- Epilogue: out = [dec_emb[2] (1024) | h_final (2048)]
__global__ void epilogue_kernel(const int* __restrict__ lenp,
                                const float* __restrict__ dec_emb,
                                const u64* __restrict__ hbuf0,
                                const u64* __restrict__ hbuf1,
                                float* __restrict__ out)
{
    int i = blockIdx.x * blockDim.x + threadIdx.x;
    int S = lenp[0] + 1;
    const u64* hb = (S & 1) ? hbuf1 : hbuf0;
    if (i < E_DIM) out[i] = dec_emb[2 * E_DIM + i];
    else if (i < E_DIM + H_DIM)
        out[i] = __uint_as_float((unsigned)hb[i - E_DIM]);
}

extern "C" void kernel_launch(void* const* d_in, const int* in_sizes, int n_in,
                              void* d_out, int out_size, void* d_ws, size_t ws_size,
                              hipStream_t stream) {
    const int*   x       = (const int*)d_in[0];
    const int*   lenp    = (const int*)d_in[1];
    const float* emb     = (const float*)d_in[2];
    const float* w_ih    = (const float*)d_in[3];
    const float* w_hh    = (const float*)d_in[4];
    const float* b_ih    = (const float*)d_in[5];
    const float* b_hh    = (const float*)d_in[6];
    const float* dec_emb = (const float*)d_in[7];
    float* out = (float*)d_out;

    char* ws = (char*)d_ws;
    float* table = (float*)ws;                              // 6,291,456 B
    u64*   hbuf0 = (u64*)(ws + (size_t)VOCAB * H3 * 4);     // 2048 u64
    u64*   hbuf1 = hbuf0 + H_DIM;                           // 2048 u64

    // zero both tagged h buffers: h_0 = {tag 0, 0.0f} (ws poisoned 0xAA)
    hipMemsetAsync(hbuf0, 0, (size_t)2 * H_DIM * sizeof(u64), stream);

    dim3 gA(H3 / 64, VOCAB / 64);  // (96, 4)
    ih_table_kernel<<<gA, 256, 0, stream>>>(emb, w_ih, b_ih, table);

    gru_persistent<<<dim3(NCOMP), dim3(TPW), 0, stream>>>(
        x, lenp, w_hh, b_hh, table, hbuf0, hbuf1);

    epilogue_kernel<<<12, 256, 0, stream>>>(lenp, dec_emb, hbuf0, hbuf1, out);
}